// Round 1
// baseline (267.054 us; speedup 1.0000x reference)
//
#include <hip/hip_runtime.h>
#include <math.h>

#define T 32
#define NEGS 0.1f
#define EPS 1e-5f

// ws layout:
//   bytes [0, 1024):   double accum[66]: [0]=sum_y [1]=sum_y2 [2..33]=S2_i [34..65]=SS2_i
//   bytes [1024, ...): float y[k]
__device__ __forceinline__ float sigm(float x) {
    return 1.0f / (1.0f + __expf(-x));
}
__device__ __forceinline__ float tanh_fast(float x) {
    float ax = fabsf(x);
    float t = __expf(2.0f * ax);
    float r = 1.0f - 2.0f / (t + 1.0f);   // t=inf -> 1, no NaN
    return copysignf(r, x);
}
__device__ __forceinline__ float lrelu(float x) {
    return x > 0.0f ? x : NEGS * x;
}

__global__ __launch_bounds__(256, 1)
void lstm_kernel(const float* __restrict__ r, const float* __restrict__ v,
                 const float* __restrict__ u,
                 const float* __restrict__ wih0, const float* __restrict__ wihr,
                 const float* __restrict__ whhp,
                 float* __restrict__ out, double* __restrict__ wsd,
                 float* __restrict__ wsy, int k)
{
    const int s = blockIdx.x * 256 + threadIdx.x;

    // hoist all weights to registers (uniform -> scalar loads)
    float wi0[4][21];
#pragma unroll
    for (int g = 0; g < 4; ++g)
#pragma unroll
        for (int j = 0; j < 21; ++j) wi0[g][j] = wih0[g * 21 + j];
    float wir[4][4];
#pragma unroll
    for (int l = 0; l < 4; ++l)
#pragma unroll
        for (int g = 0; g < 4; ++g) wir[l][g] = wihr[l * 4 + g];
    float whh[5][4];
#pragma unroll
    for (int l = 0; l < 5; ++l)
#pragma unroll
        for (int g = 0; g < 4; ++g) whh[l][g] = whhp[l * 4 + g];

    const float4* r4 = reinterpret_cast<const float4*>(r + (size_t)s * (T * 9));
    const float4* v4 = reinterpret_cast<const float4*>(v + (size_t)s * (T * 6));
    const float4* u4 = reinterpret_cast<const float4*>(u + (size_t)s * (T * 6));

    float h[5] = {0.f, 0.f, 0.f, 0.f, 0.f};
    float c[5] = {0.f, 0.f, 0.f, 0.f, 0.f};
    float y0 = 0.f;

    for (int t0 = 0; t0 < T; t0 += 4) {
        const int cb = t0 >> 2;
        float4 rb[9], vb[6], ub[6];
#pragma unroll
        for (int q = 0; q < 9; ++q) rb[q] = r4[cb * 9 + q];
#pragma unroll
        for (int q = 0; q < 6; ++q) vb[q] = v4[cb * 6 + q];
#pragma unroll
        for (int q = 0; q < 6; ++q) ub[q] = u4[cb * 6 + q];

        float rf[36], vf[24], uf[24];
#pragma unroll
        for (int q = 0; q < 9; ++q) {
            rf[4 * q] = rb[q].x; rf[4 * q + 1] = rb[q].y;
            rf[4 * q + 2] = rb[q].z; rf[4 * q + 3] = rb[q].w;
        }
#pragma unroll
        for (int q = 0; q < 6; ++q) {
            vf[4 * q] = vb[q].x; vf[4 * q + 1] = vb[q].y;
            vf[4 * q + 2] = vb[q].z; vf[4 * q + 3] = vb[q].w;
            uf[4 * q] = ub[q].x; uf[4 * q + 1] = ub[q].y;
            uf[4 * q + 2] = ub[q].z; uf[4 * q + 3] = ub[q].w;
        }

#pragma unroll
        for (int dt = 0; dt < 4; ++dt) {
            float x[21];
#pragma unroll
            for (int j = 0; j < 9; ++j) x[j] = rf[dt * 9 + j];
#pragma unroll
            for (int j = 0; j < 6; ++j) x[9 + j] = vf[dt * 6 + j];
#pragma unroll
            for (int j = 0; j < 6; ++j) x[15 + j] = uf[dt * 6 + j];

            // layer 0
            float gt[4];
#pragma unroll
            for (int g = 0; g < 4; ++g) {
                float a = whh[0][g] * h[0];
#pragma unroll
                for (int j = 0; j < 21; ++j) a = fmaf(wi0[g][j], x[j], a);
                gt[g] = a;
            }
            {
                float ii = sigm(gt[0]), ff = sigm(gt[1]);
                float gg = tanh_fast(gt[2]), oo = sigm(gt[3]);
                c[0] = ff * c[0] + ii * gg;
                h[0] = oo * tanh_fast(c[0]);
            }
            float xin = h[0];
#pragma unroll
            for (int l = 1; l < 5; ++l) {
                float g0 = fmaf(wir[l - 1][0], xin, whh[l][0] * h[l]);
                float g1 = fmaf(wir[l - 1][1], xin, whh[l][1] * h[l]);
                float g2 = fmaf(wir[l - 1][2], xin, whh[l][2] * h[l]);
                float g3 = fmaf(wir[l - 1][3], xin, whh[l][3] * h[l]);
                float ii = sigm(g0), ff = sigm(g1);
                float gg = tanh_fast(g2), oo = sigm(g3);
                c[l] = ff * c[l] + ii * gg;
                h[l] = oo * tanh_fast(c[l]);
                xin = h[l];
            }
            if (t0 + dt == 0) y0 = h[4];
        }
    }

    // outputs: dv occupies [0, 6k); hT at [6k, 11k); cT at [11k, 16k)
#pragma unroll
    for (int l = 0; l < 5; ++l) {
        out[(size_t)6 * k + (size_t)l * k + s] = h[l];
        out[(size_t)11 * k + (size_t)l * k + s] = c[l];
    }
    wsy[s] = y0;

    // block reduce sum(y), sum(y^2) -> double atomics
    float ys = y0, yq = y0 * y0;
#pragma unroll
    for (int off = 32; off; off >>= 1) {
        ys += __shfl_down(ys, off);
        yq += __shfl_down(yq, off);
    }
    __shared__ float pS[4], pQ[4];
    const int wid = threadIdx.x >> 6, lane = threadIdx.x & 63;
    if (lane == 0) { pS[wid] = ys; pQ[wid] = yq; }
    __syncthreads();
    if (threadIdx.x == 0) {
        atomicAdd(&wsd[0], (double)(pS[0] + pS[1] + pS[2] + pS[3]));
        atomicAdd(&wsd[1], (double)(pQ[0] + pQ[1] + pQ[2] + pQ[3]));
    }
}

__global__ __launch_bounds__(256)
void fc_stats_kernel(const float* __restrict__ W1, const float* __restrict__ g1v,
                     const float* __restrict__ b1v, const float* __restrict__ W2,
                     double* __restrict__ wsd, const float* __restrict__ wsy, int k)
{
    __shared__ float sW2[1024];
    __shared__ float sA[32], sBv[32];
    __shared__ float sMy;
    for (int i = threadIdx.x; i < 1024; i += 256) sW2[i] = W2[i];
    if (threadIdx.x < 32) {
        float my = (float)(wsd[0] / k);
        float vy = (float)(wsd[1] / k) - my * my;
        int j = threadIdx.x;
        float wj = W1[j];
        sA[j] = g1v[j] * wj * rsqrtf(fmaf(wj * wj, vy, EPS));
        sBv[j] = b1v[j];
        if (j == 0) sMy = my;
    }
    __syncthreads();

    const int s = blockIdx.x * 256 + threadIdx.x;
    const float yc = wsy[s] - sMy;
    float y1[32];
#pragma unroll
    for (int j = 0; j < 32; ++j) y1[j] = lrelu(fmaf(sA[j], yc, sBv[j]));

    __shared__ float pS[4][32], pQ[4][32];
    const int wid = threadIdx.x >> 6, lane = threadIdx.x & 63;
    for (int i = 0; i < 32; ++i) {
        float z = 0.f;
#pragma unroll
        for (int j = 0; j < 32; ++j) z = fmaf(sW2[i * 32 + j], y1[j], z);
        float q = z * z;
#pragma unroll
        for (int off = 32; off; off >>= 1) {
            z += __shfl_down(z, off);
            q += __shfl_down(q, off);
        }
        if (lane == 0) { pS[wid][i] = z; pQ[wid][i] = q; }
    }
    __syncthreads();
    if (threadIdx.x < 32) {
        int i = threadIdx.x;
        atomicAdd(&wsd[2 + i], (double)(pS[0][i] + pS[1][i] + pS[2][i] + pS[3][i]));
    } else if (threadIdx.x < 64) {
        int i = threadIdx.x - 32;
        atomicAdd(&wsd[34 + i], (double)(pQ[0][i] + pQ[1][i] + pQ[2][i] + pQ[3][i]));
    }
}

__global__ __launch_bounds__(256)
void fc_final_kernel(const float* __restrict__ W1, const float* __restrict__ g1v,
                     const float* __restrict__ b1v, const float* __restrict__ W2,
                     const float* __restrict__ g2v, const float* __restrict__ b2v,
                     const float* __restrict__ W3, const double* __restrict__ wsd,
                     const float* __restrict__ wsy, float* __restrict__ out, int k)
{
    __shared__ float sW2[1024], sW3[192];
    __shared__ float sA[32], sBv[32], sM2[32], sI2[32], sB2[32];
    __shared__ float sMy;
    for (int i = threadIdx.x; i < 1024; i += 256) sW2[i] = W2[i];
    if (threadIdx.x < 192) sW3[threadIdx.x] = W3[threadIdx.x];
    if (threadIdx.x < 32) {
        float my = (float)(wsd[0] / k);
        float vy = (float)(wsd[1] / k) - my * my;
        int j = threadIdx.x;
        float wj = W1[j];
        sA[j] = g1v[j] * wj * rsqrtf(fmaf(wj * wj, vy, EPS));
        sBv[j] = b1v[j];
        float m2 = (float)(wsd[2 + j] / k);
        float v2 = (float)(wsd[34 + j] / k) - m2 * m2;
        sM2[j] = m2;
        sI2[j] = g2v[j] * rsqrtf(v2 + EPS);
        sB2[j] = b2v[j];
        if (j == 0) sMy = my;
    }
    __syncthreads();

    const int s = blockIdx.x * 256 + threadIdx.x;
    const float yc = wsy[s] - sMy;
    float y1[32];
#pragma unroll
    for (int j = 0; j < 32; ++j) y1[j] = lrelu(fmaf(sA[j], yc, sBv[j]));

    float dv[6] = {0.f, 0.f, 0.f, 0.f, 0.f, 0.f};
    for (int i = 0; i < 32; ++i) {
        float z = 0.f;
#pragma unroll
        for (int j = 0; j < 32; ++j) z = fmaf(sW2[i * 32 + j], y1[j], z);
        float y2 = lrelu(fmaf(sI2[i], z - sM2[i], sB2[i]));
#pragma unroll
        for (int m = 0; m < 6; ++m) dv[m] = fmaf(sW3[m * 32 + i], y2, dv[m]);
    }
#pragma unroll
    for (int m = 0; m < 6; ++m) out[(size_t)s * 6 + m] = dv[m];
}

extern "C" void kernel_launch(void* const* d_in, const int* in_sizes, int n_in,
                              void* d_out, int out_size, void* d_ws, size_t ws_size,
                              hipStream_t stream)
{
    const float* r    = (const float*)d_in[0];
    const float* v    = (const float*)d_in[1];
    const float* u    = (const float*)d_in[2];
    const float* wih0 = (const float*)d_in[3];
    const float* wihr = (const float*)d_in[4];
    const float* whhp = (const float*)d_in[5];
    const float* W1   = (const float*)d_in[6];
    const float* g1v  = (const float*)d_in[7];
    const float* b1v  = (const float*)d_in[8];
    const float* W2   = (const float*)d_in[9];
    const float* g2v  = (const float*)d_in[10];
    const float* b2v  = (const float*)d_in[11];
    const float* W3   = (const float*)d_in[12];

    const int k = in_sizes[0] / (T * 9);   // 65536
    float* out = (float*)d_out;
    double* wsd = (double*)d_ws;
    float* wsy = (float*)((char*)d_ws + 1024);

    hipMemsetAsync(d_ws, 0, 1024, stream);

    const int blocks = k / 256;
    lstm_kernel<<<blocks, 256, 0, stream>>>(r, v, u, wih0, wihr, whhp, out, wsd, wsy, k);
    fc_stats_kernel<<<blocks, 256, 0, stream>>>(W1, g1v, b1v, W2, wsd, wsy, k);
    fc_final_kernel<<<blocks, 256, 0, stream>>>(W1, g1v, b1v, W2, g2v, b2v, W3, wsd, wsy, out, k);
}